// Round 7
// baseline (215.670 us; speedup 1.0000x reference)
//
#include <hip/hip_runtime.h>

// HeightmapNormalsLoss: fused Sobel-normals + L1 mean over two [32,1,512,512] fp32 images.
// R7: VGPR diet for the 64-reg occupancy cliff (8 waves/SIMD). 2 cols/lane (float2),
// rolled u/v state = 16 regs, no manual ILP pipeline (TLP via 32 waves/CU instead).
// Single kernel: block partials -> 64 spread atomic slots -> last block finishes.

#define IMG_H 512
#define IMG_W 512
#define BAND  8              // rows per block
#define NT    256            // 4 waves; wave s = 128-col strip s, 2 cols/lane
#define NSLOT 64
#define SLOT_STRIDE 32       // floats; 128 B between slots -> no atomic line contention

// Horizontal prefilters for one row (2 cols/lane): u = [1,0,-1], v = [1,2,1].
__device__ __forceinline__ void hfilt2(float2 x, float xh, int lane, int strip,
                                       float2& u, float2& v) {
    float xm = __shfl_up(x.y, 1, 64);     // lane-1's col1 = left neighbor of col0
    float xp = __shfl_down(x.x, 1, 64);   // lane+1's col0 = right neighbor of col1
    if (lane == 0)  xm = (strip == 0) ? x.x : xh;   // image edge clamp / cross-strip halo
    if (lane == 63) xp = (strip == 3) ? x.y : xh;
    u.x = xm  - x.y;   u.y = x.x - xp;
    v.x = xm  + 2.f * x.x + x.y;
    v.y = x.x + 2.f * x.y + xp;
}

// |n(gen) - n(tgt)| summed over 3 components for one pixel.
// n = (4gx, 4gy, sqrt(1-q)) * rsqrt(63q+1), q = gx^2+gy^2  (algebraic fold, absmax 0.0 since R3).
__device__ __forceinline__ float pixdiff(float gxa, float gya, float gxb, float gyb) {
    float qa = fmaf(gxa, gxa, gya * gya);
    float qb = fmaf(gxb, gxb, gyb * gyb);
    float ta = rsqrtf(fmaf(63.f, qa, 1.f));
    float tb = rsqrtf(fmaf(63.f, qb, 1.f));
    return fabsf(4.f * gxa * ta - 4.f * gxb * tb)
         + fabsf(4.f * gya * ta - 4.f * gyb * tb)
         + fabsf(sqrtf(1.f - qa) * ta - sqrtf(1.f - qb) * tb);
}

__global__ __launch_bounds__(NT, 8)   // 8 waves/EU -> VGPR capped at 64 (state est. ~56)
void hnl_main(const float* __restrict__ gen, const float* __restrict__ tgt,
              float* __restrict__ ws, float* __restrict__ out,
              int nblocks, float scale) {
    const int t     = threadIdx.x;
    const int strip = t >> 6;            // 0..3: 128-col strip
    const int lane  = t & 63;
    const int rbase = blockIdx.x * BAND;
    const int c0    = strip * 128 + lane * 2;

    const size_t ib = (size_t)blockIdx.y * (IMG_H * IMG_W);
    const float* gp = gen + ib;
    const float* tp = tgt + ib;

    const bool needHalo = (lane == 0 && strip > 0) || (lane == 63 && strip < 3);
    const int  haloCol  = (lane == 0) ? strip * 128 - 1 : strip * 128 + 128;

    auto rowptr = [&](const float* base, int r) {
        int rc = min(IMG_H - 1, max(0, r));              // ReplicationPad2d vertical clamp
        return base + (size_t)rc * IMG_W;
    };
    auto ld = [&](const float* rp, float2& x, float& xh) {
        x  = *reinterpret_cast<const float2*>(rp + c0);
        xh = needHalo ? rp[haloCol] : 0.f;
    };

    // prologue: rows rbase-1, rbase
    float2 x; float xh;
    float2 gup, gvp, guc, gvc, tup, tvp, tuc, tvc;
    ld(rowptr(gp, rbase - 1), x, xh); hfilt2(x, xh, lane, strip, gup, gvp);
    ld(rowptr(gp, rbase    ), x, xh); hfilt2(x, xh, lane, strip, guc, gvc);
    ld(rowptr(tp, rbase - 1), x, xh); hfilt2(x, xh, lane, strip, tup, tvp);
    ld(rowptr(tp, rbase    ), x, xh); hfilt2(x, xh, lane, strip, tuc, tvc);

    float acc = 0.f;
    #pragma unroll
    for (int i = 0; i < BAND; ++i) {
        float2 gun, gvn, tun, tvn;
        ld(rowptr(gp, rbase + i + 1), x, xh); hfilt2(x, xh, lane, strip, gun, gvn);
        ld(rowptr(tp, rbase + i + 1), x, xh); hfilt2(x, xh, lane, strip, tun, tvn);

        acc += pixdiff(gup.x + 2.f * guc.x + gun.x, gvp.x - gvn.x,
                       tup.x + 2.f * tuc.x + tun.x, tvp.x - tvn.x);
        acc += pixdiff(gup.y + 2.f * guc.y + gun.y, gvp.y - gvn.y,
                       tup.y + 2.f * tuc.y + tun.y, tvp.y - tvn.y);

        gup = guc; guc = gun; gvp = gvc; gvc = gvn;
        tup = tuc; tuc = tun; tvp = tvc; tvc = tvn;
    }

    // wave butterfly + block reduce
    #pragma unroll
    for (int o = 32; o; o >>= 1) acc += __shfl_xor(acc, o, 64);
    __shared__ float wsum[NT / 64];
    __shared__ int   isLast;
    if (lane == 0) wsum[strip] = acc;
    __syncthreads();

    float* slots = ws;                                    // 64 slots, 128 B apart
    unsigned int* counter = (unsigned int*)(ws + NSLOT * SLOT_STRIDE);
    const int bid = blockIdx.y * gridDim.x + blockIdx.x;

    if (t == 0) {
        float s = wsum[0] + wsum[1] + wsum[2] + wsum[3];
        atomicAdd(&slots[(bid & (NSLOT - 1)) * SLOT_STRIDE], s);   // device-scope
        __threadfence();
        unsigned int old = atomicAdd(counter, 1u);
        isLast = (old == (unsigned int)(nblocks - 1));
    }
    __syncthreads();

    if (isLast && t < NSLOT) {
        __threadfence();
        float v = atomicAdd(&slots[t * SLOT_STRIDE], 0.f);         // coherent read
        #pragma unroll
        for (int o = 32; o; o >>= 1) v += __shfl_xor(v, o, 64);
        if (t == 0) out[0] = v * scale;
    }
}

extern "C" void kernel_launch(void* const* d_in, const int* in_sizes, int n_in,
                              void* d_out, int out_size, void* d_ws, size_t ws_size,
                              hipStream_t stream) {
    const float* gen = (const float*)d_in[0];
    const float* tgt = (const float*)d_in[1];
    float* out = (float*)d_out;
    float* ws  = (float*)d_ws;

    const int B = in_sizes[0] / (IMG_H * IMG_W);     // 32
    const int nBands = IMG_H / BAND;                 // 64
    const int nblocks = nBands * B;                  // 2048
    const float scale = 1.f / ((float)B * 3.f * IMG_H * IMG_W);

    // zero the 64 accumulator slots + counter (d_ws is poisoned 0xAA each replay)
    hipMemsetAsync(ws, 0, (NSLOT * SLOT_STRIDE + 1) * sizeof(float), stream);

    dim3 grid(nBands, B);                            // (64, 32) = 2048 blocks x 4 waves
    hnl_main<<<grid, NT, 0, stream>>>(gen, tgt, ws, out, nblocks, scale);
}

// Round 8
// 154.080 us; speedup vs baseline: 1.3997x; 1.3997x over previous
//
#include <hip/hip_runtime.h>

// HeightmapNormalsLoss: fused Sobel-normals + L1 mean over two [32,1,512,512] fp32 images.
// R8: async-DMA LDS staging (global_load_lds w=16, ~0 VGPR cost) -> full 512-wide rows in LDS,
// scalar conflict-free LDS reads, no shuffles, no halo loads. Register state ~50 VGPR
// (under the 64-reg occupancy cliff honestly, NO launch_bounds min-wave cap).
// 40 KB LDS = 4 blocks/CU = 32 waves/CU. Fused spread-slot reduction (R7 tail, verified).

#define IMG_H 512
#define IMG_W 512
#define BAND  8              // output rows per block
#define NROWS (BAND + 2)     // staged rows (with vertical halo)
#define NT    512            // 8 waves
#define NSLOT 64
#define SLOT_STRIDE 32       // floats; 128 B between atomic slots

__device__ __forceinline__ void gld_lds16(const float* g, float* l) {
#if __has_builtin(__builtin_amdgcn_global_load_lds)
    __builtin_amdgcn_global_load_lds(
        (const __attribute__((address_space(1))) unsigned int*)g,
        (__attribute__((address_space(3))) unsigned int*)l,
        16, 0, 0);                       // per-lane global src; LDS dst = base + lane*16
#else
    // fallback: reg-staged vector copy (per-lane)
    const int lane = threadIdx.x & 63;
    reinterpret_cast<float4*>(l)[lane] =
        reinterpret_cast<const float4*>(g)[0];
#endif
}

// |n(gen) - n(tgt)| summed over 3 components for one pixel.
// n = (4gx, 4gy, sqrt(1-q)) * rsqrt(63q+1), q = gx^2+gy^2  (algebraic fold, absmax 0.0 since R3).
__device__ __forceinline__ float pixdiff(float gxa, float gya, float gxb, float gyb) {
    float qa = fmaf(gxa, gxa, gya * gya);
    float qb = fmaf(gxb, gxb, gyb * gyb);
    float ta = rsqrtf(fmaf(63.f, qa, 1.f));
    float tb = rsqrtf(fmaf(63.f, qb, 1.f));
    return fabsf(4.f * gxa * ta - 4.f * gxb * tb)
         + fabsf(4.f * gya * ta - 4.f * gyb * tb)
         + fabsf(sqrtf(1.f - qa) * ta - sqrtf(1.f - qb) * tb);
}

__global__ __launch_bounds__(NT)
void hnl_main(const float* __restrict__ gen, const float* __restrict__ tgt,
              float* __restrict__ ws, float* __restrict__ out,
              int nblocks, float scale) {
    __shared__ float tile[2][NROWS][IMG_W];      // exactly 40960 B

    const int t    = threadIdx.x;
    const int wave = t >> 6;
    const int lane = t & 63;
    const int r0   = blockIdx.x * BAND;

    const size_t ib = (size_t)blockIdx.y * (IMG_H * IMG_W);
    const float* gp = gen + ib;
    const float* tp = tgt + ib;

    // ---- stage 10 rows x 512 cols x 2 images via async DMA ----
    // 40 units: u = img*20 + row*2 + half, each = one wave-level 1 KB DMA.
    #pragma unroll
    for (int u = wave; u < 40; u += 8) {
        const int img  = u / 20;
        const int row  = (u % 20) >> 1;
        const int half = u & 1;
        int rc = min(IMG_H - 1, max(0, r0 - 1 + row));        // ReplicationPad2d vertical clamp
        const float* src = (img ? tp : gp) + (size_t)rc * IMG_W + half * 256 + lane * 4;
        gld_lds16(src, &tile[img][row][half * 256]);
    }
    __syncthreads();   // compiler drains vmcnt(0) before s_barrier -> DMA complete

    // ---- compute: 1 col/thread, rolling separable prefilters from LDS ----
    const int c  = t;                                  // 0..511
    const int cm = max(c - 1, 0);                      // horizontal edge clamp (ReplicationPad2d)
    const int cp = min(c + 1, IMG_W - 1);

    // u = x[c-1]-x[c+1] (gx row-filter), v = x[c-1]+2x[c]+x[c+1] (gy row-filter)
    auto hrow = [&](int img_, int row_, float& u_, float& v_) {
        float xm = tile[img_][row_][cm];
        float x  = tile[img_][row_][c];
        float xp = tile[img_][row_][cp];
        u_ = xm - xp;
        v_ = xm + 2.f * x + xp;
    };

    float gu0, gu1, gv0, gv1, tu0, tu1, tv0, tv1;
    hrow(0, 0, gu0, gv0); hrow(0, 1, gu1, gv1);
    hrow(1, 0, tu0, tv0); hrow(1, 1, tu1, tv1);

    float acc = 0.f;
    #pragma unroll
    for (int i = 0; i < BAND; ++i) {
        float gun, gvn, tun, tvn;
        hrow(0, i + 2, gun, gvn);
        hrow(1, i + 2, tun, tvn);
        // gx = u_{r-1} + 2u_r + u_{r+1} ; gy = v_{r-1} - v_{r+1}
        acc += pixdiff(gu0 + 2.f * gu1 + gun, gv0 - gvn,
                       tu0 + 2.f * tu1 + tun, tv0 - tvn);
        gu0 = gu1; gu1 = gun; gv0 = gv1; gv1 = gvn;
        tu0 = tu1; tu1 = tun; tv0 = tv1; tv1 = tvn;
    }

    // ---- reduce: wave butterfly -> block -> spread atomic slots -> last block ----
    #pragma unroll
    for (int o = 32; o; o >>= 1) acc += __shfl_xor(acc, o, 64);

    __syncthreads();                                   // tile reads done; reuse LDS for tail
    float* wsum = &tile[0][0][0];
    int*   flag = (int*)&tile[0][0][16];
    if (lane == 0) wsum[wave] = acc;
    __syncthreads();

    float* slots = ws;
    unsigned int* counter = (unsigned int*)(ws + NSLOT * SLOT_STRIDE);
    const int bid = blockIdx.y * gridDim.x + blockIdx.x;

    if (t == 0) {
        float s = 0.f;
        #pragma unroll
        for (int w = 0; w < 8; ++w) s += wsum[w];
        atomicAdd(&slots[(bid & (NSLOT - 1)) * SLOT_STRIDE], s);   // device-scope
        __threadfence();
        unsigned int old = atomicAdd(counter, 1u);
        flag[0] = (old == (unsigned int)(nblocks - 1));
    }
    __syncthreads();

    if (flag[0] && t < NSLOT) {
        __threadfence();
        float v = atomicAdd(&slots[t * SLOT_STRIDE], 0.f);         // coherent read
        #pragma unroll
        for (int o = 32; o; o >>= 1) v += __shfl_xor(v, o, 64);
        if (t == 0) out[0] = v * scale;
    }
}

extern "C" void kernel_launch(void* const* d_in, const int* in_sizes, int n_in,
                              void* d_out, int out_size, void* d_ws, size_t ws_size,
                              hipStream_t stream) {
    const float* gen = (const float*)d_in[0];
    const float* tgt = (const float*)d_in[1];
    float* out = (float*)d_out;
    float* ws  = (float*)d_ws;

    const int B = in_sizes[0] / (IMG_H * IMG_W);     // 32
    const int nBands = IMG_H / BAND;                 // 64
    const int nblocks = nBands * B;                  // 2048
    const float scale = 1.f / ((float)B * 3.f * IMG_H * IMG_W);

    // zero the 64 accumulator slots + counter (d_ws is poisoned 0xAA each replay)
    hipMemsetAsync(ws, 0, (NSLOT * SLOT_STRIDE + 1) * sizeof(float), stream);

    dim3 grid(nBands, B);                            // (64, 32) = 2048 blocks x 8 waves
    hnl_main<<<grid, NT, 0, stream>>>(gen, tgt, ws, out, nblocks, scale);
}

// Round 9
// 106.982 us; speedup vs baseline: 2.0159x; 1.4402x over previous
//
#include <hip/hip_runtime.h>

// HeightmapNormalsLoss: fused Sobel-normals + L1 mean over two [32,1,512,512] fp32 images.
// R9: R8's async-DMA LDS staging + scalar LDS compute (VGPR=32, no spill, 74% occ)
// with the fused atomic tail REMOVED (R7/R8's ~60-100us regression: per-block
// device-scope atomics + __threadfence L2 writeback). Two-kernel reduce (R3-R6, ~3us).

#define IMG_H 512
#define IMG_W 512
#define BAND  8              // output rows per block
#define NROWS (BAND + 2)     // staged rows (with vertical halo)
#define NT    512            // 8 waves

__device__ __forceinline__ void gld_lds16(const float* g, float* l) {
#if __has_builtin(__builtin_amdgcn_global_load_lds)
    __builtin_amdgcn_global_load_lds(
        (const __attribute__((address_space(1))) unsigned int*)g,
        (__attribute__((address_space(3))) unsigned int*)l,
        16, 0, 0);                       // per-lane global src; LDS dst = base + lane*16
#else
    const int lane = threadIdx.x & 63;
    reinterpret_cast<float4*>(l)[lane] =
        reinterpret_cast<const float4*>(g)[0];
#endif
}

// |n(gen) - n(tgt)| summed over 3 components for one pixel.
// n = (4gx, 4gy, sqrt(1-q)) * rsqrt(63q+1), q = gx^2+gy^2  (algebraic fold, absmax 0.0 since R3).
__device__ __forceinline__ float pixdiff(float gxa, float gya, float gxb, float gyb) {
    float qa = fmaf(gxa, gxa, gya * gya);
    float qb = fmaf(gxb, gxb, gyb * gyb);
    float ta = rsqrtf(fmaf(63.f, qa, 1.f));
    float tb = rsqrtf(fmaf(63.f, qb, 1.f));
    return fabsf(4.f * gxa * ta - 4.f * gxb * tb)
         + fabsf(4.f * gya * ta - 4.f * gyb * tb)
         + fabsf(sqrtf(1.f - qa) * ta - sqrtf(1.f - qb) * tb);
}

__global__ __launch_bounds__(NT)
void hnl_main(const float* __restrict__ gen, const float* __restrict__ tgt,
              float* __restrict__ partial) {
    __shared__ float tile[2][NROWS][IMG_W];      // exactly 40960 B -> 4 blocks/CU

    const int t    = threadIdx.x;
    const int wave = t >> 6;
    const int lane = t & 63;
    const int r0   = blockIdx.x * BAND;

    const size_t ib = (size_t)blockIdx.y * (IMG_H * IMG_W);
    const float* gp = gen + ib;
    const float* tp = tgt + ib;

    // ---- stage 10 rows x 512 cols x 2 images via async DMA (1 KB per instruction) ----
    #pragma unroll
    for (int u = wave; u < 40; u += 8) {
        const int img  = u / 20;
        const int row  = (u % 20) >> 1;
        const int half = u & 1;
        int rc = min(IMG_H - 1, max(0, r0 - 1 + row));        // ReplicationPad2d vertical clamp
        const float* src = (img ? tp : gp) + (size_t)rc * IMG_W + half * 256 + lane * 4;
        gld_lds16(src, &tile[img][row][half * 256]);
    }
    __syncthreads();   // drains vmcnt(0) before s_barrier -> DMA complete

    // ---- compute: 1 col/thread, rolling separable prefilters from LDS ----
    const int c  = t;                                  // 0..511
    const int cm = max(c - 1, 0);                      // horizontal edge clamp
    const int cp = min(c + 1, IMG_W - 1);

    auto hrow = [&](int img_, int row_, float& u_, float& v_) {
        float xm = tile[img_][row_][cm];
        float x  = tile[img_][row_][c];
        float xp = tile[img_][row_][cp];
        u_ = xm - xp;                  // gx row-filter [1,0,-1]
        v_ = xm + 2.f * x + xp;        // gy row-filter [1,2,1]
    };

    float gu0, gu1, gv0, gv1, tu0, tu1, tv0, tv1;
    hrow(0, 0, gu0, gv0); hrow(0, 1, gu1, gv1);
    hrow(1, 0, tu0, tv0); hrow(1, 1, tu1, tv1);

    float acc = 0.f;
    #pragma unroll
    for (int i = 0; i < BAND; ++i) {
        float gun, gvn, tun, tvn;
        hrow(0, i + 2, gun, gvn);
        hrow(1, i + 2, tun, tvn);
        // gx = u_{r-1} + 2u_r + u_{r+1} ; gy = v_{r-1} - v_{r+1}
        acc += pixdiff(gu0 + 2.f * gu1 + gun, gv0 - gvn,
                       tu0 + 2.f * tu1 + tun, tv0 - tvn);
        gu0 = gu1; gu1 = gun; gv0 = gv1; gv1 = gvn;
        tu0 = tu1; tu1 = tun; tv0 = tv1; tv1 = tvn;
    }

    // ---- wave butterfly -> block partial (NO global atomics / fences) ----
    #pragma unroll
    for (int o = 32; o; o >>= 1) acc += __shfl_xor(acc, o, 64);

    __shared__ float wsum[NT / 64];
    if (lane == 0) wsum[wave] = acc;
    __syncthreads();
    if (t == 0) {
        float s = 0.f;
        #pragma unroll
        for (int w = 0; w < NT / 64; ++w) s += wsum[w];
        partial[blockIdx.y * gridDim.x + blockIdx.x] = s;
    }
}

__global__ __launch_bounds__(256)
void hnl_reduce(const float* __restrict__ partial, float* __restrict__ out,
                int n, float scale) {
    const int t = threadIdx.x;
    float s = 0.f;
    for (int i = t; i < n; i += 256) s += partial[i];
    #pragma unroll
    for (int o = 32; o; o >>= 1) s += __shfl_xor(s, o, 64);
    __shared__ float wsum[4];
    if ((t & 63) == 0) wsum[t >> 6] = s;
    __syncthreads();
    if (t == 0) out[0] = (wsum[0] + wsum[1] + wsum[2] + wsum[3]) * scale;
}

extern "C" void kernel_launch(void* const* d_in, const int* in_sizes, int n_in,
                              void* d_out, int out_size, void* d_ws, size_t ws_size,
                              hipStream_t stream) {
    const float* gen = (const float*)d_in[0];
    const float* tgt = (const float*)d_in[1];
    float* out = (float*)d_out;
    float* ws  = (float*)d_ws;

    const int B = in_sizes[0] / (IMG_H * IMG_W);     // 32
    const int nBands = IMG_H / BAND;                 // 64
    const int nPartials = B * nBands;                // 2048
    const float scale = 1.f / ((float)B * 3.f * IMG_H * IMG_W);

    dim3 grid(nBands, B);                            // (64, 32) = 2048 blocks x 8 waves
    hnl_main<<<grid, NT, 0, stream>>>(gen, tgt, ws);
    hnl_reduce<<<1, 256, 0, stream>>>(ws, out, nPartials, scale);
}